// Round 14
// baseline (763.893 us; speedup 1.0000x reference)
//
#include <hip/hip_runtime.h>
#include <hip/hip_bf16.h>
#include <stdint.h>

// WindowAttention (Swin, shifted): x[2048,49,512] f32 -> out[2048,49,512] f32
// Pipeline (xcast FUSED into GEMM1 this round):
//   k_wprep: TILED cast+transpose weights to bf16 [N][K] (32x32 LDS tiles)
//   k_tabs : bias[h][64][64], mask[mw][64][64] f32 tables + bias2
//   k_gemm<1,0>: qkv = f32(x) @ Wt^T + bias2  (bf16 out; A reg-staged f32->bf16
//                with in-flight cvt, B via global_load_lds; counted vmcnt(12))
//   k_attn : block=window, 4 waves; swapped QK^T lane-local softmax (R10/R13)
//   k_gemm<0,1>: out = aout @ Pt^T + proj_b   (f32 out; R10 exact structure)
// GEMM core: 128x128 tile, 4 waves, BK=64, 64KB LDS double-buffer (2 blocks/CU),
// counted-vmcnt pipeline (never drained mid-loop), T2 XOR-swizzle both sides,
// T1 XCD-contiguous block swizzle, LDS-staged coalesced epilogue.

#define HEADS 16
#define NTOK  49
#define CH    512

typedef float  f32x4  __attribute__((ext_vector_type(4)));
typedef __bf16 bf16x8 __attribute__((ext_vector_type(8)));
typedef unsigned short u16;
typedef unsigned int   u32;

__device__ __forceinline__ u16 f2bf(float f) {
  return __builtin_bit_cast(u16, (__bf16)f);   // native v_cvt, RNE
}

__device__ __forceinline__ void gload16(const u16* g, u16* l) {
  __builtin_amdgcn_global_load_lds(
      (const __attribute__((address_space(1))) u32*)g,
      (__attribute__((address_space(3))) u32*)l, 16, 0, 0);
}

// ---------------- weight prep: tiled 32x32 transpose, both sides coalesced ----------------
__global__ __launch_bounds__(256) void k_wprep(const float* __restrict__ qkv_w,
                                               const float* __restrict__ proj_w,
                                               u16* __restrict__ Wt, u16* __restrict__ Pt) {
  __shared__ float tile[32][33];
  const float sc = 0.17677669529663687f;       // 32^-0.5
  int b = blockIdx.x;
  const float* src; u16* dst; int ld, tk, tn, scaleN;
  if (b < 768) { src = qkv_w; dst = Wt; ld = 1536; tk = (b / 48) * 32; tn = (b % 48) * 32; scaleN = 512; }
  else { b -= 768; src = proj_w; dst = Pt; ld = 512; tk = (b / 16) * 32; tn = (b % 16) * 32; scaleN = 0; }
  const int c = threadIdx.x & 31, r0 = threadIdx.x >> 5;
#pragma unroll
  for (int i = 0; i < 4; ++i) {
    int r = r0 + i * 8;
    tile[r][c] = src[(size_t)(tk + r) * ld + tn + c];
  }
  __syncthreads();
#pragma unroll
  for (int i = 0; i < 4; ++i) {
    int r = r0 + i * 8;
    float v = tile[c][r];
    if (tn + r < scaleN) v *= sc;
    dst[(size_t)(tn + r) * 512 + tk + c] = f2bf(v);
  }
}

// ---------------- bias/mask tables + bias2 ----------------
__global__ __launch_bounds__(256) void k_tabs(const float* __restrict__ bias_table,
                                              const float* __restrict__ qkv_b,
                                              float* __restrict__ biasM,
                                              float* __restrict__ maskT,
                                              float* __restrict__ bias2) {
  const float sc = 0.17677669529663687f;
  int tid = blockIdx.x * 256 + threadIdx.x;
  if (tid < 1536) bias2[tid] = qkv_b[tid] * (tid < 512 ? sc : 1.f);
  if (tid < 16 * 4096) {
    int h = tid >> 12, rc = tid & 4095, r = rc >> 6, c = rc & 63;
    float v = -1e30f;
    if (r < NTOK && c < NTOK) {
      int ih = r / 7, iw = r - ih * 7, jh = c / 7, jw = c - jh * 7;
      v = bias_table[((ih - jh + 6) * 13 + (iw - jw + 6)) * HEADS + h];
    }
    biasM[tid] = v;
  } else {
    int t2 = tid - 65536;
    int mw = t2 >> 12, rc = t2 & 4095, r = rc >> 6, c = rc & 63;
    float v = 0.f;
    if (r < NTOK && c < NTOK) {
      int mwR = (mw >> 3) * 7, mwC = (mw & 7) * 7;
      int ih = r / 7, iw = r - ih * 7, jh = c / 7, jw = c - jh * 7;
      int gih = mwR + ih, giw = mwC + iw, gjh = mwR + jh, gjw = mwC + jw;
      int ri = (gih < 49 ? 0 : (gih < 53 ? 1 : 2)) * 3 + (giw < 49 ? 0 : (giw < 53 ? 1 : 2));
      int rj = (gjh < 49 ? 0 : (gjh < 53 ? 1 : 2)) * 3 + (gjw < 49 ? 0 : (gjw < 53 ? 1 : 2));
      v = (ri != rj) ? -100.f : 0.f;
    }
    maskT[t2] = v;
  }
}

// ---------------- GEMM: C[M][Nn] = A[M][K] @ Bt[Nn][K]^T + bias ----------------
// A_F32=1: A is f32, reg-staged (load f32x4 -> cvt -> swizzled ds_write_b128).
// A_F32=0: A is bf16 via global_load_lds (R10 exact).
template<int A_F32, int OUT_F32>
__global__ __launch_bounds__(256, 2) void k_gemm(const void* __restrict__ Ap,
                                                 const u16* __restrict__ Bt,
                                                 const float* __restrict__ bias,
                                                 void* __restrict__ Cp,
                                                 int M, int Nn, int K, int nbn) {
  __shared__ u16 smem[2 * 16384];              // 64 KiB: 2 x {A 128x64 | B 128x64}
  const int t   = threadIdx.x;
  const int q8  = gridDim.x >> 3;
  const int bid = (blockIdx.x & 7) * q8 + (blockIdx.x >> 3);
  const int cb  = bid % nbn, rb = bid / nbn;
  const int row0 = rb << 7, col0 = cb << 7;
  const int lane = t & 63, w = t >> 6;
  const int wr = (w >> 1) << 6, wc = (w & 1) << 6;
  const int lm = lane & 15, lk = lane >> 4;

  const f32x4 fz = {0.f, 0.f, 0.f, 0.f};
  f32x4 acc[4][4];
#pragma unroll
  for (int i = 0; i < 4; i++)
#pragma unroll
    for (int j = 0; j < 4; j++) acc[i][j] = fz;

  // bf16-A staging geometry (A_F32=0) and B staging (both): chunk c ^= row&7
  int gr[4], gc[4], gdb[4];
#pragma unroll
  for (int i = 0; i < 4; ++i) {
    int q = (i << 8) + t;
    gr[i]  = q >> 3;
    gc[i]  = (((q & 7) ^ (gr[i] & 7)) << 3);
    gdb[i] = ((i << 8) + (t & 192)) << 3;
  }
  // read-side swizzled offsets (loop-invariant)
  int offA[4], offB[4];
#pragma unroll
  for (int i = 0; i < 4; ++i) {
    int rowA = wr + i * 16 + lm;
    offA[i] = rowA * 64 + ((lk ^ (rowA & 7)) << 3);
    int rowB = wc + i * 16 + lm;
    offB[i] = rowB * 64 + ((lk ^ (rowB & 7)) << 3);
  }

  auto stageB = [&](int p, int kt) {
    const int kb = kt << 6;
    u16* dB = smem + p * 16384 + 8192;
#pragma unroll
    for (int i = 0; i < 4; ++i)
      gload16(Bt + (size_t)(col0 + gr[i]) * K + kb + gc[i], dB + gdb[i]);
  };
  auto stageA16 = [&](int p, int kt) {
    const int kb = kt << 6;
    const u16* A = (const u16*)Ap;
    u16* dA = smem + p * 16384;
#pragma unroll
    for (int i = 0; i < 4; ++i)
      gload16(A + (size_t)(row0 + gr[i]) * K + kb + gc[i], dA + gdb[i]);
  };

  // f32-A reg staging: thread t owns row rAst = t>>1, half hA = t&1 (32 floats)
  const int rAst = t >> 1, hA = t & 1;
  float4 rf[8];
  auto loadAf = [&](int kt) {
    const float* xA = (const float*)Ap;
    const int kb = kt << 6;
    const float* src = xA + (size_t)(row0 + rAst) * K + kb + hA * 32;
#pragma unroll
    for (int i = 0; i < 8; ++i)
      rf[i] = *(const float4*)(src + i * 4);
  };
  auto writeAf = [&](int p) {
    u16* dA = smem + p * 16384;
#pragma unroll
    for (int j = 0; j < 4; ++j) {
      u16 pk[8] = {f2bf(rf[2*j].x),   f2bf(rf[2*j].y),   f2bf(rf[2*j].z),   f2bf(rf[2*j].w),
                   f2bf(rf[2*j+1].x), f2bf(rf[2*j+1].y), f2bf(rf[2*j+1].z), f2bf(rf[2*j+1].w)};
      int sw = ((hA * 4 + j) ^ (rAst & 7)) << 3;
      *(int4*)(dA + rAst * 64 + sw) = *(const int4*)pk;
    }
  };

  const int nk = K >> 6;
  if constexpr (A_F32) { loadAf(0); } else { stageA16(0, 0); }
  stageB(0, 0);
  int p = 0;
  for (int kt = 0; kt < nk; ++kt) {
    if constexpr (A_F32) {
      writeAf(p);                               // cvt+ds_write A(kt) (auto-waits its loads)
      if (kt + 1 < nk) {
        loadAf(kt + 1);                         // 8 f32x4 in flight across the MFMA phase
        stageB(p ^ 1, kt + 1);                  // 4 gload_lds
        // 12 newest = A-regs(kt+1) 8 + B(kt+1) 4 -> B(kt) landed; lgkm: our ds_writes done
        asm volatile("s_waitcnt vmcnt(12) lgkmcnt(0)" ::: "memory");
      } else {
        asm volatile("s_waitcnt vmcnt(0) lgkmcnt(0)" ::: "memory");
      }
    } else {
      if (kt + 1 < nk) {
        stageA16(p ^ 1, kt + 1);
        stageB(p ^ 1, kt + 1);
        asm volatile("s_waitcnt vmcnt(8)" ::: "memory");   // 8 newest = tile kt+1
      } else {
        asm volatile("s_waitcnt vmcnt(0)" ::: "memory");
      }
    }
    __builtin_amdgcn_s_barrier();               // all waves' tile-kt data in LDS
    asm volatile("" ::: "memory");
    const u16* sA = smem + p * 16384;
    const u16* sB = sA + 8192;
    bf16x8 a[4][2], b[4][2];
#pragma unroll
    for (int mi = 0; mi < 4; ++mi) {
      a[mi][0] = *(const bf16x8*)(sA + offA[mi]);
      a[mi][1] = *(const bf16x8*)(sA + (offA[mi] ^ 32));
    }
#pragma unroll
    for (int ni = 0; ni < 4; ++ni) {
      b[ni][0] = *(const bf16x8*)(sB + offB[ni]);
      b[ni][1] = *(const bf16x8*)(sB + (offB[ni] ^ 32));
    }
#pragma unroll
    for (int kk = 0; kk < 2; ++kk)
#pragma unroll
      for (int mi = 0; mi < 4; ++mi)
#pragma unroll
        for (int ni = 0; ni < 4; ++ni)
          acc[mi][ni] = __builtin_amdgcn_mfma_f32_16x16x32_bf16(a[mi][kk], b[ni][kk],
                                                                acc[mi][ni], 0, 0, 0);
    asm volatile("" ::: "memory");
    __builtin_amdgcn_s_barrier();               // readers done; NO vmcnt drain
    asm volatile("" ::: "memory");
    p ^= 1;
  }

  if constexpr (!OUT_F32) {
#pragma unroll
    for (int mi = 0; mi < 4; ++mi)
#pragma unroll
      for (int ni = 0; ni < 4; ++ni) {
        int col = wc + ni * 16 + lm;
        float bv = bias[col0 + col];
#pragma unroll
        for (int r = 0; r < 4; ++r)
          smem[(wr + mi * 16 + lk * 4 + r) * 136 + col] = f2bf(acc[mi][ni][r] + bv);
      }
    __syncthreads();
    const int rr = t >> 1, seg = t & 1;
    u16* dst = (u16*)Cp + (size_t)(row0 + rr) * Nn + col0 + seg * 64;
    const u16* src = smem + rr * 136 + seg * 64;
#pragma unroll
    for (int i = 0; i < 8; ++i)
      *(int4*)(dst + i * 8) = *(const int4*)(src + i * 8);
  } else {
    float* smf = (float*)smem;
    for (int half = 0; half < 2; ++half) {
      __syncthreads();
      if ((w >> 1) == half) {
#pragma unroll
        for (int mi = 0; mi < 4; ++mi)
#pragma unroll
          for (int ni = 0; ni < 4; ++ni) {
            int col = wc + ni * 16 + lm;
            float bv = bias[col0 + col];
#pragma unroll
            for (int r = 0; r < 4; ++r)
              smf[(mi * 16 + lk * 4 + r) * 132 + col] = acc[mi][ni][r] + bv;
          }
      }
      __syncthreads();
      const int rr = t >> 2, seg = t & 3;
      float* dst = (float*)Cp + (size_t)(row0 + half * 64 + rr) * Nn + col0 + seg * 32;
      const float* src = smf + rr * 132 + seg * 32;
#pragma unroll
      for (int i = 0; i < 8; ++i)
        *(float4*)(dst + i * 4) = *(const float4*)(src + i * 4);
    }
  }
}

// ---------------- fused window attention (R10 structure, VGPR-lean) ----------------
__global__ __launch_bounds__(256) void k_attn(const u16* __restrict__ qkv,
                                              const float* __restrict__ biasM,
                                              const float* __restrict__ maskT,
                                              u16* __restrict__ aout) {
  __shared__ u16 sm[4 * 3264];      // per wave: sV 32x68 (V^T) + sP 16x68
  const int wdx = blockIdx.x;
  const int mw  = wdx & 63;
  const int t   = threadIdx.x;
  const int wv  = t >> 6;
  const int l   = t & 63;
  const int lm  = l & 15, lk = l >> 4;
  const size_t tb = (size_t)wdx * NTOK;
  const u16* base = qkv + tb * 1536;
  u16* sV = sm + wv * 3264;
  u16* sP = sV + 2176;

  const int4  iz = make_int4(0, 0, 0, 0);
  const f32x4 fz = {0.f, 0.f, 0.f, 0.f};
  const float* mT = maskT + (mw << 12);

  for (int hh = 0; hh < 4; ++hh) {
    const int h = (wv << 2) + hh;

    {
      int4 vv[4] = {iz, iz, iz, iz};
      if (l < NTOK) {
        const u16* vp = base + (size_t)l * 1536 + 1024 + h * 32;
#pragma unroll
        for (int i = 0; i < 4; ++i) vv[i] = *(const int4*)(vp + i * 8);
      }
      const u16* u = (const u16*)vv;
#pragma unroll
      for (int d = 0; d < 32; ++d) sV[d * 68 + l] = u[d];
    }

    bf16x8 kf[4];
#pragma unroll
    for (int ni = 0; ni < 4; ++ni) {
      int krow = ni * 16 + lm;
      int4 ki = (krow < NTOK)
        ? *(const int4*)(base + (size_t)krow * 1536 + 512 + h * 32 + lk * 8) : iz;
      kf[ni] = __builtin_bit_cast(bf16x8, ki);
    }

    bf16x8 vb[2][2];
#pragma unroll
    for (int kt = 0; kt < 2; ++kt)
#pragma unroll
      for (int df = 0; df < 2; ++df)
        vb[kt][df] = *(const bf16x8*)(sV + (df * 16 + lm) * 68 + kt * 32 + lk * 8);

    const float* bM = biasM + (h << 12);

#pragma unroll
    for (int mi = 0; mi < 4; ++mi) {
      const int qrow = mi * 16 + lm;
      int4 qi = (qrow < NTOK)
        ? *(const int4*)(base + (size_t)qrow * 1536 + h * 32 + lk * 8) : iz;
      bf16x8 qf = __builtin_bit_cast(bf16x8, qi);

      f32x4 st[4];
#pragma unroll
      for (int ni = 0; ni < 4; ++ni) {
        const int o4 = (qrow << 6) + ni * 16 + lk * 4;
        float4 b4 = *(const float4*)(bM + o4);
        float4 m4 = *(const float4*)(mT + o4);
        f32x4 ci = {b4.x + m4.x, b4.y + m4.y, b4.z + m4.z, b4.w + m4.w};
        st[ni] = __builtin_amdgcn_mfma_f32_16x16x32_bf16(kf[ni], qf, ci, 0, 0, 0);
      }

      float mx = -3e38f;
#pragma unroll
      for (int ni = 0; ni < 4; ++ni)
#pragma unroll
        for (int r = 0; r < 4; ++r) mx = fmaxf(mx, st[ni][r]);
      mx = fmaxf(mx, __shfl_xor(mx, 16, 64));
      mx = fmaxf(mx, __shfl_xor(mx, 32, 64));
      float sum = 0.f;
#pragma unroll
      for (int ni = 0; ni < 4; ++ni)
#pragma unroll
        for (int r = 0; r < 4; ++r) {
          float p = __expf(st[ni][r] - mx);
          st[ni][r] = p;
          sum += p;
        }
      sum += __shfl_xor(sum, 16, 64);
      sum += __shfl_xor(sum, 32, 64);
      const float rinv = __builtin_amdgcn_rcpf(sum);

#pragma unroll
      for (int ni = 0; ni < 4; ++ni) {
        u16 pk[4] = {f2bf(st[ni][0] * rinv), f2bf(st[ni][1] * rinv),
                     f2bf(st[ni][2] * rinv), f2bf(st[ni][3] * rinv)};
        *(int2*)(sP + lm * 68 + ni * 16 + lk * 4) = *(const int2*)pk;
      }

      f32x4 o0 = fz, o1 = fz;
#pragma unroll
      for (int kt = 0; kt < 2; ++kt) {
        bf16x8 pa = *(const bf16x8*)(sP + lm * 68 + kt * 32 + lk * 8);
        o0 = __builtin_amdgcn_mfma_f32_16x16x32_bf16(pa, vb[kt][0], o0, 0, 0, 0);
        o1 = __builtin_amdgcn_mfma_f32_16x16x32_bf16(pa, vb[kt][1], o1, 0, 0, 0);
      }

#pragma unroll
      for (int r = 0; r < 4; ++r) {
        int tok = mi * 16 + lk * 4 + r;
        if (tok < NTOK) {
          size_t ob = (tb + tok) * CH + h * 32;
          aout[ob + lm]      = f2bf(o0[r]);
          aout[ob + 16 + lm] = f2bf(o1[r]);
        }
      }
    }
  }
}

extern "C" void kernel_launch(void* const* d_in, const int* in_sizes, int n_in,
                              void* d_out, int out_size, void* d_ws, size_t ws_size,
                              hipStream_t stream) {
  const float* x      = (const float*)d_in[0];
  const float* qkv_b  = (const float*)d_in[2];
  const float* proj_b = (const float*)d_in[4];
  const float* btab   = (const float*)d_in[5];

  char* ws   = (char*)d_ws;
  u16* Wt    = (u16*)ws;                                  // 1,572,864 B
  u16* Pt    = (u16*)(ws + 1572864);                      //   524,288 B
  u16* qkv   = (u16*)(ws + 2097152);                      // 308,281,344 B
  u16* aout  = (u16*)(ws + 2097152 + 308281344ull);       // 102,760,448 B
  float* biasM = (float*)(ws + 2097152 + 308281344ull + 102760448ull);  // 262,144 B
  float* maskT = biasM + 65536;                           // 1,048,576 B
  float* bias2 = maskT + 262144;                          //     6,144 B
  float* out = (float*)d_out;

  k_wprep<<<1024, 256, 0, stream>>>((const float*)d_in[1], (const float*)d_in[3], Wt, Pt);
  k_tabs<<<1280, 256, 0, stream>>>(btab, qkv_b, biasM, maskT, bias2);
  k_gemm<1, 0><<<784 * 12, 256, 0, stream>>>((const void*)x, Wt, bias2, (void*)qkv,
                                             100352, 1536, 512, 12);
  k_attn<<<2048, 256, 0, stream>>>(qkv, biasM, maskT, aout);
  k_gemm<0, 1><<<784 * 4, 256, 0, stream>>>((const void*)aout, Pt, proj_b, (void*)out,
                                            100352, 512, 512, 4);
}

// Round 15
// 699.151 us; speedup vs baseline: 1.0926x; 1.0926x over previous
//
#include <hip/hip_runtime.h>
#include <hip/hip_bf16.h>
#include <stdint.h>

// WindowAttention (Swin, shifted): x[2048,49,512] f32 -> out[2048,49,512] f32
// Pipeline:
//   k_wprep: TILED cast+transpose weights to bf16 [N][K] (32x32 LDS tiles)
//   k_xcast: x f32 -> bf16 (R14's GEMM-fused cast REVERTED: reg-staged A put
//            load latency on the critical path every iter -> 259->511us)
//   k_ctab : ctab[h][mw][64][64] = bias+mask combined (16.7MB, L3-resident)
//            + bias2; falls back to split biasM/maskT tables if ws_size short
//   k_gemm<0>: qkv = xb @ Wt^T + bias2     (bf16 out; R10/R13 exact)
//   k_attn : block=window, 4 waves x 4 heads; swapped QK^T lane-local softmax;
//            V+K+Q batch-issued per head (one HBM-latency shadow, not five);
//            combined-table C operand. VGPR-bounded (no cross-head prefetch).
//   k_gemm<1>: out = aout @ Pt^T + proj_b  (f32 out)
// GEMM: 128x128 tile, 4 waves, BK=64, 64KB LDS dbuf, counted vmcnt(8) pipeline
// (never drained mid-loop), T2 XOR-swizzle, T1 XCD swizzle, LDS epilogue.

#define HEADS 16
#define NTOK  49
#define CH    512

typedef float  f32x4  __attribute__((ext_vector_type(4)));
typedef __bf16 bf16x8 __attribute__((ext_vector_type(8)));
typedef unsigned short u16;
typedef unsigned int   u32;

__device__ __forceinline__ u16 f2bf(float f) {
  return __builtin_bit_cast(u16, (__bf16)f);   // native v_cvt, RNE
}

__device__ __forceinline__ void gload16(const u16* g, u16* l) {
  __builtin_amdgcn_global_load_lds(
      (const __attribute__((address_space(1))) u32*)g,
      (__attribute__((address_space(3))) u32*)l, 16, 0, 0);
}

// ---------------- weight prep: tiled 32x32 transpose ----------------
__global__ __launch_bounds__(256) void k_wprep(const float* __restrict__ qkv_w,
                                               const float* __restrict__ proj_w,
                                               u16* __restrict__ Wt, u16* __restrict__ Pt) {
  __shared__ float tile[32][33];
  const float sc = 0.17677669529663687f;
  int b = blockIdx.x;
  const float* src; u16* dst; int ld, tk, tn, scaleN;
  if (b < 768) { src = qkv_w; dst = Wt; ld = 1536; tk = (b / 48) * 32; tn = (b % 48) * 32; scaleN = 512; }
  else { b -= 768; src = proj_w; dst = Pt; ld = 512; tk = (b / 16) * 32; tn = (b % 16) * 32; scaleN = 0; }
  const int c = threadIdx.x & 31, r0 = threadIdx.x >> 5;
#pragma unroll
  for (int i = 0; i < 4; ++i) {
    int r = r0 + i * 8;
    tile[r][c] = src[(size_t)(tk + r) * ld + tn + c];
  }
  __syncthreads();
#pragma unroll
  for (int i = 0; i < 4; ++i) {
    int r = r0 + i * 8;
    float v = tile[c][r];
    if (tn + r < scaleN) v *= sc;
    dst[(size_t)(tn + r) * 512 + tk + c] = f2bf(v);
  }
}

// ---------------- x cast: f32 -> bf16 ----------------
__global__ __launch_bounds__(256) void k_xcast(const float* __restrict__ x,
                                               u16* __restrict__ xb) {
  int tid = blockIdx.x * 256 + threadIdx.x;
  const float4* xv = (const float4*)x;
  float4 a = xv[tid * 2], b = xv[tid * 2 + 1];
  u16 o[8] = {f2bf(a.x), f2bf(a.y), f2bf(a.z), f2bf(a.w),
              f2bf(b.x), f2bf(b.y), f2bf(b.z), f2bf(b.w)};
  ((int4*)xb)[tid] = *(const int4*)o;
}

// ---------------- combined table: ctab[h][mw][r][c] = bias + mask ----------------
__global__ __launch_bounds__(256) void k_ctab(const float* __restrict__ bias_table,
                                              const float* __restrict__ qkv_b,
                                              float* __restrict__ ctab,
                                              float* __restrict__ bias2) {
  int tid = blockIdx.x * 256 + threadIdx.x;    // < 16*64*4096
  if (tid < 1536) bias2[tid] = qkv_b[tid] * (tid < 512 ? 0.17677669529663687f : 1.f);
  int h  = tid >> 18, mw = (tid >> 12) & 63, r = (tid >> 6) & 63, c = tid & 63;
  float v = -1e30f;
  if (r < NTOK && c < NTOK) {
    int ih = r / 7, iw = r - ih * 7, jh = c / 7, jw = c - jh * 7;
    v = bias_table[((ih - jh + 6) * 13 + (iw - jw + 6)) * HEADS + h];
    int mwR = (mw >> 3) * 7, mwC = (mw & 7) * 7;
    int gih = mwR + ih, giw = mwC + iw, gjh = mwR + jh, gjw = mwC + jw;
    int ri = (gih < 49 ? 0 : (gih < 53 ? 1 : 2)) * 3 + (giw < 49 ? 0 : (giw < 53 ? 1 : 2));
    int rj = (gjh < 49 ? 0 : (gjh < 53 ? 1 : 2)) * 3 + (gjw < 49 ? 0 : (gjw < 53 ? 1 : 2));
    if (ri != rj) v -= 100.f;
  }
  ctab[tid] = v;
}

// ---------------- fallback split tables ----------------
__global__ __launch_bounds__(256) void k_tabs(const float* __restrict__ bias_table,
                                              const float* __restrict__ qkv_b,
                                              float* __restrict__ biasM,
                                              float* __restrict__ maskT,
                                              float* __restrict__ bias2) {
  const float sc = 0.17677669529663687f;
  int tid = blockIdx.x * 256 + threadIdx.x;
  if (tid < 1536) bias2[tid] = qkv_b[tid] * (tid < 512 ? sc : 1.f);
  if (tid < 16 * 4096) {
    int h = tid >> 12, rc = tid & 4095, r = rc >> 6, c = rc & 63;
    float v = -1e30f;
    if (r < NTOK && c < NTOK) {
      int ih = r / 7, iw = r - ih * 7, jh = c / 7, jw = c - jh * 7;
      v = bias_table[((ih - jh + 6) * 13 + (iw - jw + 6)) * HEADS + h];
    }
    biasM[tid] = v;
  } else {
    int t2 = tid - 65536;
    int mw = t2 >> 12, rc = t2 & 4095, r = rc >> 6, c = rc & 63;
    float v = 0.f;
    if (r < NTOK && c < NTOK) {
      int mwR = (mw >> 3) * 7, mwC = (mw & 7) * 7;
      int ih = r / 7, iw = r - ih * 7, jh = c / 7, jw = c - jh * 7;
      int gih = mwR + ih, giw = mwC + iw, gjh = mwR + jh, gjw = mwC + jw;
      int ri = (gih < 49 ? 0 : (gih < 53 ? 1 : 2)) * 3 + (giw < 49 ? 0 : (giw < 53 ? 1 : 2));
      int rj = (gjh < 49 ? 0 : (gjh < 53 ? 1 : 2)) * 3 + (gjw < 49 ? 0 : (gjw < 53 ? 1 : 2));
      v = (ri != rj) ? -100.f : 0.f;
    }
    maskT[t2] = v;
  }
}

// ---------------- GEMM: C[M][Nn] = A[M][K] @ Bt[Nn][K]^T + bias  (R13 exact) ----------------
template<int OUT_F32>
__global__ __launch_bounds__(256, 2) void k_gemm(const u16* __restrict__ A,
                                                 const u16* __restrict__ Bt,
                                                 const float* __restrict__ bias,
                                                 void* __restrict__ Cp,
                                                 int M, int Nn, int K, int nbn) {
  __shared__ u16 smem[2 * 16384];
  const int t   = threadIdx.x;
  const int q8  = gridDim.x >> 3;
  const int bid = (blockIdx.x & 7) * q8 + (blockIdx.x >> 3);
  const int cb  = bid % nbn, rb = bid / nbn;
  const int row0 = rb << 7, col0 = cb << 7;
  const int lane = t & 63, w = t >> 6;
  const int wr = (w >> 1) << 6, wc = (w & 1) << 6;
  const int lm = lane & 15, lk = lane >> 4;

  const f32x4 fz = {0.f, 0.f, 0.f, 0.f};
  f32x4 acc[4][4];
#pragma unroll
  for (int i = 0; i < 4; i++)
#pragma unroll
    for (int j = 0; j < 4; j++) acc[i][j] = fz;

  int gr[4], gc[4], gdb[4];
#pragma unroll
  for (int i = 0; i < 4; ++i) {
    int q = (i << 8) + t;
    gr[i]  = q >> 3;
    gc[i]  = (((q & 7) ^ (gr[i] & 7)) << 3);
    gdb[i] = ((i << 8) + (t & 192)) << 3;
  }
  int offA[4], offB[4];
#pragma unroll
  for (int i = 0; i < 4; ++i) {
    int rowA = wr + i * 16 + lm;
    offA[i] = rowA * 64 + ((lk ^ (rowA & 7)) << 3);
    int rowB = wc + i * 16 + lm;
    offB[i] = rowB * 64 + ((lk ^ (rowB & 7)) << 3);
  }

  auto stage = [&](int p, int kt) {
    const int kb = kt << 6;
    u16* dA = smem + p * 16384;
    u16* dB = dA + 8192;
#pragma unroll
    for (int i = 0; i < 4; ++i) {
      gload16(A  + (size_t)(row0 + gr[i]) * K + kb + gc[i], dA + gdb[i]);
      gload16(Bt + (size_t)(col0 + gr[i]) * K + kb + gc[i], dB + gdb[i]);
    }
  };

  const int nk = K >> 6;
  stage(0, 0);
  int p = 0;
  for (int kt = 0; kt < nk; ++kt) {
    if (kt + 1 < nk) {
      stage(p ^ 1, kt + 1);
      asm volatile("s_waitcnt vmcnt(8)" ::: "memory");
    } else {
      asm volatile("s_waitcnt vmcnt(0)" ::: "memory");
    }
    __builtin_amdgcn_s_barrier();
    asm volatile("" ::: "memory");
    const u16* sA = smem + p * 16384;
    const u16* sB = sA + 8192;
    bf16x8 a[4][2], b[4][2];
#pragma unroll
    for (int mi = 0; mi < 4; ++mi) {
      a[mi][0] = *(const bf16x8*)(sA + offA[mi]);
      a[mi][1] = *(const bf16x8*)(sA + (offA[mi] ^ 32));
    }
#pragma unroll
    for (int ni = 0; ni < 4; ++ni) {
      b[ni][0] = *(const bf16x8*)(sB + offB[ni]);
      b[ni][1] = *(const bf16x8*)(sB + (offB[ni] ^ 32));
    }
#pragma unroll
    for (int kk = 0; kk < 2; ++kk)
#pragma unroll
      for (int mi = 0; mi < 4; ++mi)
#pragma unroll
        for (int ni = 0; ni < 4; ++ni)
          acc[mi][ni] = __builtin_amdgcn_mfma_f32_16x16x32_bf16(a[mi][kk], b[ni][kk],
                                                                acc[mi][ni], 0, 0, 0);
    asm volatile("" ::: "memory");
    __builtin_amdgcn_s_barrier();
    asm volatile("" ::: "memory");
    p ^= 1;
  }

  if constexpr (!OUT_F32) {
#pragma unroll
    for (int mi = 0; mi < 4; ++mi)
#pragma unroll
      for (int ni = 0; ni < 4; ++ni) {
        int col = wc + ni * 16 + lm;
        float bv = bias[col0 + col];
#pragma unroll
        for (int r = 0; r < 4; ++r)
          smem[(wr + mi * 16 + lk * 4 + r) * 136 + col] = f2bf(acc[mi][ni][r] + bv);
      }
    __syncthreads();
    const int rr = t >> 1, seg = t & 1;
    u16* dst = (u16*)Cp + (size_t)(row0 + rr) * Nn + col0 + seg * 64;
    const u16* src = smem + rr * 136 + seg * 64;
#pragma unroll
    for (int i = 0; i < 8; ++i)
      *(int4*)(dst + i * 8) = *(const int4*)(src + i * 8);
  } else {
    float* smf = (float*)smem;
    for (int half = 0; half < 2; ++half) {
      __syncthreads();
      if ((w >> 1) == half) {
#pragma unroll
        for (int mi = 0; mi < 4; ++mi)
#pragma unroll
          for (int ni = 0; ni < 4; ++ni) {
            int col = wc + ni * 16 + lm;
            float bv = bias[col0 + col];
#pragma unroll
            for (int r = 0; r < 4; ++r)
              smf[(mi * 16 + lk * 4 + r) * 132 + col] = acc[mi][ni][r] + bv;
          }
      }
      __syncthreads();
      const int rr = t >> 2, seg = t & 3;
      float* dst = (float*)Cp + (size_t)(row0 + half * 64 + rr) * Nn + col0 + seg * 32;
      const float* src = smf + rr * 132 + seg * 32;
#pragma unroll
      for (int i = 0; i < 8; ++i)
        *(float4*)(dst + i * 4) = *(const float4*)(src + i * 4);
    }
  }
}

// ---------------- fused window attention ----------------
// CTAB=1: combined table + V/K/Q batch-issued per head (one latency shadow).
// CTAB=0: R13 fallback (split tables, per-mi Q load).
template<int CTAB>
__global__ __launch_bounds__(256) void k_attn(const u16* __restrict__ qkv,
                                              const float* __restrict__ tab0,
                                              const float* __restrict__ tab1,
                                              u16* __restrict__ aout) {
  __shared__ u16 sm[4 * 3264];      // per wave: sV 32x68 (V^T) + sP 16x68
  const int wdx = blockIdx.x;
  const int mw  = wdx & 63;
  const int t   = threadIdx.x;
  const int wv  = t >> 6;
  const int l   = t & 63;
  const int lm  = l & 15, lk = l >> 4;
  const size_t tb = (size_t)wdx * NTOK;
  const u16* base = qkv + tb * 1536;
  u16* sV = sm + wv * 3264;
  u16* sP = sV + 2176;

  const int4  iz = make_int4(0, 0, 0, 0);
  const f32x4 fz = {0.f, 0.f, 0.f, 0.f};

  for (int hh = 0; hh < 4; ++hh) {
    const int h = (wv << 2) + hh;

    // batch-issue V (4), K (4), and (CTAB) Q (4) -- one HBM-latency shadow
    int4 vv[4];
    const u16* vp = base + (size_t)l * 1536 + 1024 + h * 32;
#pragma unroll
    for (int i = 0; i < 4; ++i)
      vv[i] = (l < NTOK) ? *(const int4*)(vp + i * 8) : iz;
    bf16x8 kf[4];
#pragma unroll
    for (int ni = 0; ni < 4; ++ni) {
      int krow = ni * 16 + lm;
      int4 ki = (krow < NTOK)
        ? *(const int4*)(base + (size_t)krow * 1536 + 512 + h * 32 + lk * 8) : iz;
      kf[ni] = __builtin_bit_cast(bf16x8, ki);
    }
    int4 qh0 = iz, qh1 = iz, qh2 = iz, qh3 = iz;
    if constexpr (CTAB) {
      if (lm < NTOK)       qh0 = *(const int4*)(base + (size_t)(lm)      * 1536 + h * 32 + lk * 8);
      if (16 + lm < NTOK)  qh1 = *(const int4*)(base + (size_t)(16 + lm) * 1536 + h * 32 + lk * 8);
      if (32 + lm < NTOK)  qh2 = *(const int4*)(base + (size_t)(32 + lm) * 1536 + h * 32 + lk * 8);
      if (48 + lm < NTOK)  qh3 = *(const int4*)(base + (size_t)(48 + lm) * 1536 + h * 32 + lk * 8);
    }

    // V^T stage (waits only the V loads)
    {
      const u16* u = (const u16*)vv;
#pragma unroll
      for (int d = 0; d < 32; ++d) sV[d * 68 + l] = u[d];
    }
    bf16x8 vb[2][2];
#pragma unroll
    for (int kt = 0; kt < 2; ++kt)
#pragma unroll
      for (int df = 0; df < 2; ++df)
        vb[kt][df] = *(const bf16x8*)(sV + (df * 16 + lm) * 68 + kt * 32 + lk * 8);

    const float* bM;
    const float* mT = nullptr;
    if constexpr (CTAB) bM = tab0 + ((size_t)((h << 6) + mw) << 12);
    else { bM = tab0 + (h << 12); mT = tab1 + (mw << 12); }

#pragma unroll
    for (int mi = 0; mi < 4; ++mi) {
      const int qrow = mi * 16 + lm;
      bf16x8 qf;
      if constexpr (CTAB) {
        int4 qi = (mi == 0) ? qh0 : (mi == 1) ? qh1 : (mi == 2) ? qh2 : qh3;
        qf = __builtin_bit_cast(bf16x8, qi);
      } else {
        int4 qi = (qrow < NTOK)
          ? *(const int4*)(base + (size_t)qrow * 1536 + h * 32 + lk * 8) : iz;
        qf = __builtin_bit_cast(bf16x8, qi);
      }

      f32x4 st[4];
#pragma unroll
      for (int ni = 0; ni < 4; ++ni) {
        const int o4 = (qrow << 6) + ni * 16 + lk * 4;
        f32x4 ci;
        if constexpr (CTAB) {
          float4 cv = *(const float4*)(bM + o4);
          ci = (f32x4){cv.x, cv.y, cv.z, cv.w};
        } else {
          float4 b4 = *(const float4*)(bM + o4);
          float4 m4 = *(const float4*)(mT + o4);
          ci = (f32x4){b4.x + m4.x, b4.y + m4.y, b4.z + m4.z, b4.w + m4.w};
        }
        st[ni] = __builtin_amdgcn_mfma_f32_16x16x32_bf16(kf[ni], qf, ci, 0, 0, 0);
      }

      float mx = -3e38f;
#pragma unroll
      for (int ni = 0; ni < 4; ++ni)
#pragma unroll
        for (int r = 0; r < 4; ++r) mx = fmaxf(mx, st[ni][r]);
      mx = fmaxf(mx, __shfl_xor(mx, 16, 64));
      mx = fmaxf(mx, __shfl_xor(mx, 32, 64));
      float sum = 0.f;
#pragma unroll
      for (int ni = 0; ni < 4; ++ni)
#pragma unroll
        for (int r = 0; r < 4; ++r) {
          float p = __expf(st[ni][r] - mx);
          st[ni][r] = p;
          sum += p;
        }
      sum += __shfl_xor(sum, 16, 64);
      sum += __shfl_xor(sum, 32, 64);
      const float rinv = __builtin_amdgcn_rcpf(sum);

#pragma unroll
      for (int ni = 0; ni < 4; ++ni) {
        u16 pk[4] = {f2bf(st[ni][0] * rinv), f2bf(st[ni][1] * rinv),
                     f2bf(st[ni][2] * rinv), f2bf(st[ni][3] * rinv)};
        *(int2*)(sP + lm * 68 + ni * 16 + lk * 4) = *(const int2*)pk;
      }

      f32x4 o0 = fz, o1 = fz;
#pragma unroll
      for (int kt = 0; kt < 2; ++kt) {
        bf16x8 pa = *(const bf16x8*)(sP + lm * 68 + kt * 32 + lk * 8);
        o0 = __builtin_amdgcn_mfma_f32_16x16x32_bf16(pa, vb[kt][0], o0, 0, 0, 0);
        o1 = __builtin_amdgcn_mfma_f32_16x16x32_bf16(pa, vb[kt][1], o1, 0, 0, 0);
      }

#pragma unroll
      for (int r = 0; r < 4; ++r) {
        int tok = mi * 16 + lk * 4 + r;
        if (tok < NTOK) {
          size_t ob = (tb + tok) * CH + h * 32;
          aout[ob + lm]      = f2bf(o0[r]);
          aout[ob + 16 + lm] = f2bf(o1[r]);
        }
      }
    }
  }
}

extern "C" void kernel_launch(void* const* d_in, const int* in_sizes, int n_in,
                              void* d_out, int out_size, void* d_ws, size_t ws_size,
                              hipStream_t stream) {
  const float* x      = (const float*)d_in[0];
  const float* qkv_b  = (const float*)d_in[2];
  const float* proj_b = (const float*)d_in[4];
  const float* btab   = (const float*)d_in[5];

  char* ws   = (char*)d_ws;
  u16* Wt    = (u16*)ws;                                  // 1,572,864 B
  u16* Pt    = (u16*)(ws + 1572864);                      //   524,288 B
  u16* qkv   = (u16*)(ws + 2097152);                      // 308,281,344 B
  u16* aout  = (u16*)(ws + 2097152 + 308281344ull);       // 102,760,448 B (aliased xb)
  u16* xb    = aout;                                      // dead once attn writes aout
  char* tail = ws + 413138944ull;
  float* out = (float*)d_out;

  k_wprep<<<1024, 256, 0, stream>>>((const float*)d_in[1], (const float*)d_in[3], Wt, Pt);
  k_xcast<<<25088, 256, 0, stream>>>(x, xb);

  const size_t need_ctab = 413138944ull + 8192 + 16777216ull;   // ~430 MB
  if (ws_size >= need_ctab) {
    float* bias2 = (float*)tail;                          // 6,144 B
    float* ctab  = (float*)(tail + 8192);                 // 16,777,216 B
    k_ctab<<<16384, 256, 0, stream>>>(btab, qkv_b, ctab, bias2);
    k_gemm<0><<<784 * 12, 256, 0, stream>>>(xb, Wt, bias2, (void*)qkv, 100352, 1536, 512, 12);
    k_attn<1><<<2048, 256, 0, stream>>>(qkv, ctab, nullptr, aout);
  } else {
    float* biasM = (float*)tail;                          // 262,144 B
    float* maskT = biasM + 65536;                         // 1,048,576 B
    float* bias2 = maskT + 262144;                        //     6,144 B
    k_tabs<<<1280, 256, 0, stream>>>(btab, qkv_b, biasM, maskT, bias2);
    k_gemm<0><<<784 * 12, 256, 0, stream>>>(xb, Wt, bias2, (void*)qkv, 100352, 1536, 512, 12);
    k_attn<0><<<2048, 256, 0, stream>>>(qkv, biasM, maskT, aout);
  }
  k_gemm<1><<<784 * 4, 256, 0, stream>>>(aout, Pt, proj_b, (void*)out, 100352, 512, 512, 4);
}

// Round 16
// 677.585 us; speedup vs baseline: 1.1274x; 1.0318x over previous
//
#include <hip/hip_runtime.h>
#include <hip/hip_bf16.h>
#include <stdint.h>

// WindowAttention (Swin, shifted): x[2048,49,512] f32 -> out[2048,49,512] f32
// Pipeline (R13 config + attn Q-hoist only; R15's ctab REVERTED -- 16.7MB
// table doesn't fit per-XCD L2, streamed 512MB -> attn +100us):
//   k_wprep: TILED cast+transpose weights to bf16 [N][K] (32x32 LDS tiles)
//   k_xcast: x f32 -> bf16
//   k_tabs : split bias[h][64][64] + mask[mw][64][64] tables (1.3MB, L2-resident)
//   k_gemm<0>: qkv = xb @ Wt^T + bias2     (bf16 out)
//   k_attn : block=window, 4 waves x 4 heads; swapped QK^T lane-local softmax;
//            V+K+Q batch-issued per head (one HBM-latency shadow, not five --
//            R15 validated: VGPR stays ~60, occupancy rises).
//   k_gemm<1>: out = aout @ Pt^T + proj_b  (f32 out)
// GEMM: 128x128 tile, 4 waves, BK=64, 64KB LDS dbuf, counted vmcnt(8) pipeline
// (never drained mid-loop), T2 XOR-swizzle, T1 XCD swizzle, LDS epilogue.

#define HEADS 16
#define NTOK  49
#define CH    512

typedef float  f32x4  __attribute__((ext_vector_type(4)));
typedef __bf16 bf16x8 __attribute__((ext_vector_type(8)));
typedef unsigned short u16;
typedef unsigned int   u32;

__device__ __forceinline__ u16 f2bf(float f) {
  return __builtin_bit_cast(u16, (__bf16)f);   // native v_cvt, RNE
}

__device__ __forceinline__ void gload16(const u16* g, u16* l) {
  __builtin_amdgcn_global_load_lds(
      (const __attribute__((address_space(1))) u32*)g,
      (__attribute__((address_space(3))) u32*)l, 16, 0, 0);
}

// ---------------- weight prep: tiled 32x32 transpose ----------------
__global__ __launch_bounds__(256) void k_wprep(const float* __restrict__ qkv_w,
                                               const float* __restrict__ proj_w,
                                               u16* __restrict__ Wt, u16* __restrict__ Pt) {
  __shared__ float tile[32][33];
  const float sc = 0.17677669529663687f;
  int b = blockIdx.x;
  const float* src; u16* dst; int ld, tk, tn, scaleN;
  if (b < 768) { src = qkv_w; dst = Wt; ld = 1536; tk = (b / 48) * 32; tn = (b % 48) * 32; scaleN = 512; }
  else { b -= 768; src = proj_w; dst = Pt; ld = 512; tk = (b / 16) * 32; tn = (b % 16) * 32; scaleN = 0; }
  const int c = threadIdx.x & 31, r0 = threadIdx.x >> 5;
#pragma unroll
  for (int i = 0; i < 4; ++i) {
    int r = r0 + i * 8;
    tile[r][c] = src[(size_t)(tk + r) * ld + tn + c];
  }
  __syncthreads();
#pragma unroll
  for (int i = 0; i < 4; ++i) {
    int r = r0 + i * 8;
    float v = tile[c][r];
    if (tn + r < scaleN) v *= sc;
    dst[(size_t)(tn + r) * 512 + tk + c] = f2bf(v);
  }
}

// ---------------- x cast: f32 -> bf16 ----------------
__global__ __launch_bounds__(256) void k_xcast(const float* __restrict__ x,
                                               u16* __restrict__ xb) {
  int tid = blockIdx.x * 256 + threadIdx.x;
  const float4* xv = (const float4*)x;
  float4 a = xv[tid * 2], b = xv[tid * 2 + 1];
  u16 o[8] = {f2bf(a.x), f2bf(a.y), f2bf(a.z), f2bf(a.w),
              f2bf(b.x), f2bf(b.y), f2bf(b.z), f2bf(b.w)};
  ((int4*)xb)[tid] = *(const int4*)o;
}

// ---------------- split tables + bias2 ----------------
__global__ __launch_bounds__(256) void k_tabs(const float* __restrict__ bias_table,
                                              const float* __restrict__ qkv_b,
                                              float* __restrict__ biasM,
                                              float* __restrict__ maskT,
                                              float* __restrict__ bias2) {
  const float sc = 0.17677669529663687f;
  int tid = blockIdx.x * 256 + threadIdx.x;
  if (tid < 1536) bias2[tid] = qkv_b[tid] * (tid < 512 ? sc : 1.f);
  if (tid < 16 * 4096) {
    int h = tid >> 12, rc = tid & 4095, r = rc >> 6, c = rc & 63;
    float v = -1e30f;
    if (r < NTOK && c < NTOK) {
      int ih = r / 7, iw = r - ih * 7, jh = c / 7, jw = c - jh * 7;
      v = bias_table[((ih - jh + 6) * 13 + (iw - jw + 6)) * HEADS + h];
    }
    biasM[tid] = v;
  } else {
    int t2 = tid - 65536;
    int mw = t2 >> 12, rc = t2 & 4095, r = rc >> 6, c = rc & 63;
    float v = 0.f;
    if (r < NTOK && c < NTOK) {
      int mwR = (mw >> 3) * 7, mwC = (mw & 7) * 7;
      int ih = r / 7, iw = r - ih * 7, jh = c / 7, jw = c - jh * 7;
      int gih = mwR + ih, giw = mwC + iw, gjh = mwR + jh, gjw = mwC + jw;
      int ri = (gih < 49 ? 0 : (gih < 53 ? 1 : 2)) * 3 + (giw < 49 ? 0 : (giw < 53 ? 1 : 2));
      int rj = (gjh < 49 ? 0 : (gjh < 53 ? 1 : 2)) * 3 + (gjw < 49 ? 0 : (gjw < 53 ? 1 : 2));
      v = (ri != rj) ? -100.f : 0.f;
    }
    maskT[t2] = v;
  }
}

// ---------------- GEMM: C[M][Nn] = A[M][K] @ Bt[Nn][K]^T + bias  (R13 exact) ----------------
template<int OUT_F32>
__global__ __launch_bounds__(256, 2) void k_gemm(const u16* __restrict__ A,
                                                 const u16* __restrict__ Bt,
                                                 const float* __restrict__ bias,
                                                 void* __restrict__ Cp,
                                                 int M, int Nn, int K, int nbn) {
  __shared__ u16 smem[2 * 16384];
  const int t   = threadIdx.x;
  const int q8  = gridDim.x >> 3;
  const int bid = (blockIdx.x & 7) * q8 + (blockIdx.x >> 3);
  const int cb  = bid % nbn, rb = bid / nbn;
  const int row0 = rb << 7, col0 = cb << 7;
  const int lane = t & 63, w = t >> 6;
  const int wr = (w >> 1) << 6, wc = (w & 1) << 6;
  const int lm = lane & 15, lk = lane >> 4;

  const f32x4 fz = {0.f, 0.f, 0.f, 0.f};
  f32x4 acc[4][4];
#pragma unroll
  for (int i = 0; i < 4; i++)
#pragma unroll
    for (int j = 0; j < 4; j++) acc[i][j] = fz;

  int gr[4], gc[4], gdb[4];
#pragma unroll
  for (int i = 0; i < 4; ++i) {
    int q = (i << 8) + t;
    gr[i]  = q >> 3;
    gc[i]  = (((q & 7) ^ (gr[i] & 7)) << 3);
    gdb[i] = ((i << 8) + (t & 192)) << 3;
  }
  int offA[4], offB[4];
#pragma unroll
  for (int i = 0; i < 4; ++i) {
    int rowA = wr + i * 16 + lm;
    offA[i] = rowA * 64 + ((lk ^ (rowA & 7)) << 3);
    int rowB = wc + i * 16 + lm;
    offB[i] = rowB * 64 + ((lk ^ (rowB & 7)) << 3);
  }

  auto stage = [&](int p, int kt) {
    const int kb = kt << 6;
    u16* dA = smem + p * 16384;
    u16* dB = dA + 8192;
#pragma unroll
    for (int i = 0; i < 4; ++i) {
      gload16(A  + (size_t)(row0 + gr[i]) * K + kb + gc[i], dA + gdb[i]);
      gload16(Bt + (size_t)(col0 + gr[i]) * K + kb + gc[i], dB + gdb[i]);
    }
  };

  const int nk = K >> 6;
  stage(0, 0);
  int p = 0;
  for (int kt = 0; kt < nk; ++kt) {
    if (kt + 1 < nk) {
      stage(p ^ 1, kt + 1);
      asm volatile("s_waitcnt vmcnt(8)" ::: "memory");
    } else {
      asm volatile("s_waitcnt vmcnt(0)" ::: "memory");
    }
    __builtin_amdgcn_s_barrier();
    asm volatile("" ::: "memory");
    const u16* sA = smem + p * 16384;
    const u16* sB = sA + 8192;
    bf16x8 a[4][2], b[4][2];
#pragma unroll
    for (int mi = 0; mi < 4; ++mi) {
      a[mi][0] = *(const bf16x8*)(sA + offA[mi]);
      a[mi][1] = *(const bf16x8*)(sA + (offA[mi] ^ 32));
    }
#pragma unroll
    for (int ni = 0; ni < 4; ++ni) {
      b[ni][0] = *(const bf16x8*)(sB + offB[ni]);
      b[ni][1] = *(const bf16x8*)(sB + (offB[ni] ^ 32));
    }
#pragma unroll
    for (int kk = 0; kk < 2; ++kk)
#pragma unroll
      for (int mi = 0; mi < 4; ++mi)
#pragma unroll
        for (int ni = 0; ni < 4; ++ni)
          acc[mi][ni] = __builtin_amdgcn_mfma_f32_16x16x32_bf16(a[mi][kk], b[ni][kk],
                                                                acc[mi][ni], 0, 0, 0);
    asm volatile("" ::: "memory");
    __builtin_amdgcn_s_barrier();
    asm volatile("" ::: "memory");
    p ^= 1;
  }

  if constexpr (!OUT_F32) {
#pragma unroll
    for (int mi = 0; mi < 4; ++mi)
#pragma unroll
      for (int ni = 0; ni < 4; ++ni) {
        int col = wc + ni * 16 + lm;
        float bv = bias[col0 + col];
#pragma unroll
        for (int r = 0; r < 4; ++r)
          smem[(wr + mi * 16 + lk * 4 + r) * 136 + col] = f2bf(acc[mi][ni][r] + bv);
      }
    __syncthreads();
    const int rr = t >> 1, seg = t & 1;
    u16* dst = (u16*)Cp + (size_t)(row0 + rr) * Nn + col0 + seg * 64;
    const u16* src = smem + rr * 136 + seg * 64;
#pragma unroll
    for (int i = 0; i < 8; ++i)
      *(int4*)(dst + i * 8) = *(const int4*)(src + i * 8);
  } else {
    float* smf = (float*)smem;
    for (int half = 0; half < 2; ++half) {
      __syncthreads();
      if ((w >> 1) == half) {
#pragma unroll
        for (int mi = 0; mi < 4; ++mi)
#pragma unroll
          for (int ni = 0; ni < 4; ++ni) {
            int col = wc + ni * 16 + lm;
            float bv = bias[col0 + col];
#pragma unroll
            for (int r = 0; r < 4; ++r)
              smf[(mi * 16 + lk * 4 + r) * 132 + col] = acc[mi][ni][r] + bv;
          }
      }
      __syncthreads();
      const int rr = t >> 2, seg = t & 3;
      float* dst = (float*)Cp + (size_t)(row0 + half * 64 + rr) * Nn + col0 + seg * 32;
      const float* src = smf + rr * 132 + seg * 32;
#pragma unroll
      for (int i = 0; i < 8; ++i)
        *(float4*)(dst + i * 4) = *(const float4*)(src + i * 4);
    }
  }
}

// ---------------- fused window attention (R13 + V/K/Q batch-issue) ----------------
// Block = window, 4 waves; wave wv handles heads 4wv..4wv+3 sequentially.
// Swapped QK^T (mfma(K,Q)): lane (lm,lk) holds S[q=lm+16mi][k=ni*16+lk*4+r];
// softmax row lives in 4 lanes {lm,+16,+32,+48} -> 2-shuffle reduce.
// Per head: ALL 12 VMEM loads (V 4, K 4, Q 4) issue back-to-back -> one
// HBM-latency shadow. Split L2-resident tables as MFMA C operand.
__global__ __launch_bounds__(256) void k_attn(const u16* __restrict__ qkv,
                                              const float* __restrict__ biasM,
                                              const float* __restrict__ maskT,
                                              u16* __restrict__ aout) {
  __shared__ u16 sm[4 * 3264];      // per wave: sV 32x68 (V^T) + sP 16x68
  const int wdx = blockIdx.x;
  const int mw  = wdx & 63;
  const int t   = threadIdx.x;
  const int wv  = t >> 6;
  const int l   = t & 63;
  const int lm  = l & 15, lk = l >> 4;
  const size_t tb = (size_t)wdx * NTOK;
  const u16* base = qkv + tb * 1536;
  u16* sV = sm + wv * 3264;
  u16* sP = sV + 2176;

  const int4  iz = make_int4(0, 0, 0, 0);
  const f32x4 fz = {0.f, 0.f, 0.f, 0.f};
  const float* mT = maskT + (mw << 12);

  for (int hh = 0; hh < 4; ++hh) {
    const int h = (wv << 2) + hh;

    // batch-issue V (4), K (4), Q (4) -- one HBM-latency shadow for the head
    int4 vv[4];
    const u16* vp = base + (size_t)l * 1536 + 1024 + h * 32;
#pragma unroll
    for (int i = 0; i < 4; ++i)
      vv[i] = (l < NTOK) ? *(const int4*)(vp + i * 8) : iz;
    bf16x8 kf[4];
#pragma unroll
    for (int ni = 0; ni < 4; ++ni) {
      int krow = ni * 16 + lm;
      int4 ki = (krow < NTOK)
        ? *(const int4*)(base + (size_t)krow * 1536 + 512 + h * 32 + lk * 8) : iz;
      kf[ni] = __builtin_bit_cast(bf16x8, ki);
    }
    int4 qh0 = iz, qh1 = iz, qh2 = iz, qh3 = iz;
    if (lm < NTOK)       qh0 = *(const int4*)(base + (size_t)(lm)      * 1536 + h * 32 + lk * 8);
    if (16 + lm < NTOK)  qh1 = *(const int4*)(base + (size_t)(16 + lm) * 1536 + h * 32 + lk * 8);
    if (32 + lm < NTOK)  qh2 = *(const int4*)(base + (size_t)(32 + lm) * 1536 + h * 32 + lk * 8);
    if (48 + lm < NTOK)  qh3 = *(const int4*)(base + (size_t)(48 + lm) * 1536 + h * 32 + lk * 8);

    // V^T stage (waits only the V loads)
    {
      const u16* u = (const u16*)vv;
#pragma unroll
      for (int d = 0; d < 32; ++d) sV[d * 68 + l] = u[d];
    }
    bf16x8 vb[2][2];
#pragma unroll
    for (int kt = 0; kt < 2; ++kt)
#pragma unroll
      for (int df = 0; df < 2; ++df)
        vb[kt][df] = *(const bf16x8*)(sV + (df * 16 + lm) * 68 + kt * 32 + lk * 8);

    const float* bM = biasM + (h << 12);

#pragma unroll
    for (int mi = 0; mi < 4; ++mi) {
      const int qrow = mi * 16 + lm;
      int4 qi = (mi == 0) ? qh0 : (mi == 1) ? qh1 : (mi == 2) ? qh2 : qh3;
      bf16x8 qf = __builtin_bit_cast(bf16x8, qi);

      f32x4 st[4];
#pragma unroll
      for (int ni = 0; ni < 4; ++ni) {
        const int o4 = (qrow << 6) + ni * 16 + lk * 4;
        float4 b4 = *(const float4*)(bM + o4);
        float4 m4 = *(const float4*)(mT + o4);
        f32x4 ci = {b4.x + m4.x, b4.y + m4.y, b4.z + m4.z, b4.w + m4.w};
        st[ni] = __builtin_amdgcn_mfma_f32_16x16x32_bf16(kf[ni], qf, ci, 0, 0, 0);
      }

      float mx = -3e38f;
#pragma unroll
      for (int ni = 0; ni < 4; ++ni)
#pragma unroll
        for (int r = 0; r < 4; ++r) mx = fmaxf(mx, st[ni][r]);
      mx = fmaxf(mx, __shfl_xor(mx, 16, 64));
      mx = fmaxf(mx, __shfl_xor(mx, 32, 64));
      float sum = 0.f;
#pragma unroll
      for (int ni = 0; ni < 4; ++ni)
#pragma unroll
        for (int r = 0; r < 4; ++r) {
          float p = __expf(st[ni][r] - mx);
          st[ni][r] = p;
          sum += p;
        }
      sum += __shfl_xor(sum, 16, 64);
      sum += __shfl_xor(sum, 32, 64);
      const float rinv = __builtin_amdgcn_rcpf(sum);

#pragma unroll
      for (int ni = 0; ni < 4; ++ni) {
        u16 pk[4] = {f2bf(st[ni][0] * rinv), f2bf(st[ni][1] * rinv),
                     f2bf(st[ni][2] * rinv), f2bf(st[ni][3] * rinv)};
        *(int2*)(sP + lm * 68 + ni * 16 + lk * 4) = *(const int2*)pk;
      }

      f32x4 o0 = fz, o1 = fz;
#pragma unroll
      for (int kt = 0; kt < 2; ++kt) {
        bf16x8 pa = *(const bf16x8*)(sP + lm * 68 + kt * 32 + lk * 8);
        o0 = __builtin_amdgcn_mfma_f32_16x16x32_bf16(pa, vb[kt][0], o0, 0, 0, 0);
        o1 = __builtin_amdgcn_mfma_f32_16x16x32_bf16(pa, vb[kt][1], o1, 0, 0, 0);
      }

#pragma unroll
      for (int r = 0; r < 4; ++r) {
        int tok = mi * 16 + lk * 4 + r;
        if (tok < NTOK) {
          size_t ob = (tb + tok) * CH + h * 32;
          aout[ob + lm]      = f2bf(o0[r]);
          aout[ob + 16 + lm] = f2bf(o1[r]);
        }
      }
    }
  }
}

extern "C" void kernel_launch(void* const* d_in, const int* in_sizes, int n_in,
                              void* d_out, int out_size, void* d_ws, size_t ws_size,
                              hipStream_t stream) {
  const float* x      = (const float*)d_in[0];
  const float* qkv_b  = (const float*)d_in[2];
  const float* proj_b = (const float*)d_in[4];
  const float* btab   = (const float*)d_in[5];

  char* ws   = (char*)d_ws;
  u16* Wt    = (u16*)ws;                                  // 1,572,864 B
  u16* Pt    = (u16*)(ws + 1572864);                      //   524,288 B
  u16* qkv   = (u16*)(ws + 2097152);                      // 308,281,344 B
  u16* aout  = (u16*)(ws + 2097152 + 308281344ull);       // 102,760,448 B (aliased xb)
  u16* xb    = aout;                                      // dead once attn writes aout
  float* biasM = (float*)(ws + 2097152 + 308281344ull + 102760448ull);  // 262,144 B
  float* maskT = biasM + 65536;                           // 1,048,576 B
  float* bias2 = maskT + 262144;                          //     6,144 B
  float* out = (float*)d_out;

  k_wprep<<<1024, 256, 0, stream>>>((const float*)d_in[1], (const float*)d_in[3], Wt, Pt);
  k_xcast<<<25088, 256, 0, stream>>>(x, xb);
  k_tabs<<<1280, 256, 0, stream>>>(btab, qkv_b, biasM, maskT, bias2);
  k_gemm<0><<<784 * 12, 256, 0, stream>>>(xb, Wt, bias2, (void*)qkv, 100352, 1536, 512, 12);
  k_attn<<<2048, 256, 0, stream>>>(qkv, biasM, maskT, aout);
  k_gemm<1><<<784 * 4, 256, 0, stream>>>(aout, Pt, proj_b, (void*)out, 100352, 512, 512, 4);
}

// Round 18
// 597.662 us; speedup vs baseline: 1.2781x; 1.1337x over previous
//
#include <hip/hip_runtime.h>
#include <hip/hip_bf16.h>
#include <stdint.h>

// WindowAttention (Swin, shifted): x[2048,49,512] f32 -> out[2048,49,512] f32
// FINAL: exact R13 configuration (best measured: 598us, deterministic).
//   k_wprep: TILED cast+transpose weights to bf16 [N][K] (32x32 LDS tiles)
//   k_xcast: x f32 -> bf16
//   k_tabs : split bias[h][64][64] + mask[mw][64][64] tables (1.3MB, L2-resident)
//   k_gemm<0>: qkv = xb @ Wt^T + bias2     (bf16 out)
//   k_attn : block=window, 4 waves x 4 heads; swapped QK^T lane-local softmax
//            (VGPR ~76; every hoist/occupancy variant tried regressed or raced)
//   k_gemm<1>: out = aout @ Pt^T + proj_b  (f32 out)
// GEMM: 128x128 tile, 4 waves, BK=64, 64KB LDS dbuf, counted vmcnt(8) pipeline
// (never drained mid-loop), T2 XOR-swizzle, T1 XCD swizzle, LDS epilogue.

#define HEADS 16
#define NTOK  49
#define CH    512

typedef float  f32x4  __attribute__((ext_vector_type(4)));
typedef __bf16 bf16x8 __attribute__((ext_vector_type(8)));
typedef unsigned short u16;
typedef unsigned int   u32;

__device__ __forceinline__ u16 f2bf(float f) {
  return __builtin_bit_cast(u16, (__bf16)f);   // native v_cvt, RNE
}

__device__ __forceinline__ void gload16(const u16* g, u16* l) {
  __builtin_amdgcn_global_load_lds(
      (const __attribute__((address_space(1))) u32*)g,
      (__attribute__((address_space(3))) u32*)l, 16, 0, 0);
}

// ---------------- weight prep: tiled 32x32 transpose ----------------
__global__ __launch_bounds__(256) void k_wprep(const float* __restrict__ qkv_w,
                                               const float* __restrict__ proj_w,
                                               u16* __restrict__ Wt, u16* __restrict__ Pt) {
  __shared__ float tile[32][33];
  const float sc = 0.17677669529663687f;
  int b = blockIdx.x;
  const float* src; u16* dst; int ld, tk, tn, scaleN;
  if (b < 768) { src = qkv_w; dst = Wt; ld = 1536; tk = (b / 48) * 32; tn = (b % 48) * 32; scaleN = 512; }
  else { b -= 768; src = proj_w; dst = Pt; ld = 512; tk = (b / 16) * 32; tn = (b % 16) * 32; scaleN = 0; }
  const int c = threadIdx.x & 31, r0 = threadIdx.x >> 5;
#pragma unroll
  for (int i = 0; i < 4; ++i) {
    int r = r0 + i * 8;
    tile[r][c] = src[(size_t)(tk + r) * ld + tn + c];
  }
  __syncthreads();
#pragma unroll
  for (int i = 0; i < 4; ++i) {
    int r = r0 + i * 8;
    float v = tile[c][r];
    if (tn + r < scaleN) v *= sc;
    dst[(size_t)(tn + r) * 512 + tk + c] = f2bf(v);
  }
}

// ---------------- x cast: f32 -> bf16 ----------------
__global__ __launch_bounds__(256) void k_xcast(const float* __restrict__ x,
                                               u16* __restrict__ xb) {
  int tid = blockIdx.x * 256 + threadIdx.x;
  const float4* xv = (const float4*)x;
  float4 a = xv[tid * 2], b = xv[tid * 2 + 1];
  u16 o[8] = {f2bf(a.x), f2bf(a.y), f2bf(a.z), f2bf(a.w),
              f2bf(b.x), f2bf(b.y), f2bf(b.z), f2bf(b.w)};
  ((int4*)xb)[tid] = *(const int4*)o;
}

// ---------------- split tables + bias2 ----------------
__global__ __launch_bounds__(256) void k_tabs(const float* __restrict__ bias_table,
                                              const float* __restrict__ qkv_b,
                                              float* __restrict__ biasM,
                                              float* __restrict__ maskT,
                                              float* __restrict__ bias2) {
  const float sc = 0.17677669529663687f;
  int tid = blockIdx.x * 256 + threadIdx.x;
  if (tid < 1536) bias2[tid] = qkv_b[tid] * (tid < 512 ? sc : 1.f);
  if (tid < 16 * 4096) {
    int h = tid >> 12, rc = tid & 4095, r = rc >> 6, c = rc & 63;
    float v = -1e30f;
    if (r < NTOK && c < NTOK) {
      int ih = r / 7, iw = r - ih * 7, jh = c / 7, jw = c - jh * 7;
      v = bias_table[((ih - jh + 6) * 13 + (iw - jw + 6)) * HEADS + h];
    }
    biasM[tid] = v;
  } else {
    int t2 = tid - 65536;
    int mw = t2 >> 12, rc = t2 & 4095, r = rc >> 6, c = rc & 63;
    float v = 0.f;
    if (r < NTOK && c < NTOK) {
      int mwR = (mw >> 3) * 7, mwC = (mw & 7) * 7;
      int ih = r / 7, iw = r - ih * 7, jh = c / 7, jw = c - jh * 7;
      int gih = mwR + ih, giw = mwC + iw, gjh = mwR + jh, gjw = mwC + jw;
      int ri = (gih < 49 ? 0 : (gih < 53 ? 1 : 2)) * 3 + (giw < 49 ? 0 : (giw < 53 ? 1 : 2));
      int rj = (gjh < 49 ? 0 : (gjh < 53 ? 1 : 2)) * 3 + (gjw < 49 ? 0 : (gjw < 53 ? 1 : 2));
      v = (ri != rj) ? -100.f : 0.f;
    }
    maskT[t2] = v;
  }
}

// ---------------- GEMM: C[M][Nn] = A[M][K] @ Bt[Nn][K]^T + bias ----------------
template<int OUT_F32>
__global__ __launch_bounds__(256, 2) void k_gemm(const u16* __restrict__ A,
                                                 const u16* __restrict__ Bt,
                                                 const float* __restrict__ bias,
                                                 void* __restrict__ Cp,
                                                 int M, int Nn, int K, int nbn) {
  __shared__ u16 smem[2 * 16384];
  const int t   = threadIdx.x;
  const int q8  = gridDim.x >> 3;
  const int bid = (blockIdx.x & 7) * q8 + (blockIdx.x >> 3);
  const int cb  = bid % nbn, rb = bid / nbn;
  const int row0 = rb << 7, col0 = cb << 7;
  const int lane = t & 63, w = t >> 6;
  const int wr = (w >> 1) << 6, wc = (w & 1) << 6;
  const int lm = lane & 15, lk = lane >> 4;

  const f32x4 fz = {0.f, 0.f, 0.f, 0.f};
  f32x4 acc[4][4];
#pragma unroll
  for (int i = 0; i < 4; i++)
#pragma unroll
    for (int j = 0; j < 4; j++) acc[i][j] = fz;

  int gr[4], gc[4], gdb[4];
#pragma unroll
  for (int i = 0; i < 4; ++i) {
    int q = (i << 8) + t;
    gr[i]  = q >> 3;
    gc[i]  = (((q & 7) ^ (gr[i] & 7)) << 3);
    gdb[i] = ((i << 8) + (t & 192)) << 3;
  }
  int offA[4], offB[4];
#pragma unroll
  for (int i = 0; i < 4; ++i) {
    int rowA = wr + i * 16 + lm;
    offA[i] = rowA * 64 + ((lk ^ (rowA & 7)) << 3);
    int rowB = wc + i * 16 + lm;
    offB[i] = rowB * 64 + ((lk ^ (rowB & 7)) << 3);
  }

  auto stage = [&](int p, int kt) {
    const int kb = kt << 6;
    u16* dA = smem + p * 16384;
    u16* dB = dA + 8192;
#pragma unroll
    for (int i = 0; i < 4; ++i) {
      gload16(A  + (size_t)(row0 + gr[i]) * K + kb + gc[i], dA + gdb[i]);
      gload16(Bt + (size_t)(col0 + gr[i]) * K + kb + gc[i], dB + gdb[i]);
    }
  };

  const int nk = K >> 6;
  stage(0, 0);
  int p = 0;
  for (int kt = 0; kt < nk; ++kt) {
    if (kt + 1 < nk) {
      stage(p ^ 1, kt + 1);
      asm volatile("s_waitcnt vmcnt(8)" ::: "memory");
    } else {
      asm volatile("s_waitcnt vmcnt(0)" ::: "memory");
    }
    __builtin_amdgcn_s_barrier();
    asm volatile("" ::: "memory");
    const u16* sA = smem + p * 16384;
    const u16* sB = sA + 8192;
    bf16x8 a[4][2], b[4][2];
#pragma unroll
    for (int mi = 0; mi < 4; ++mi) {
      a[mi][0] = *(const bf16x8*)(sA + offA[mi]);
      a[mi][1] = *(const bf16x8*)(sA + (offA[mi] ^ 32));
    }
#pragma unroll
    for (int ni = 0; ni < 4; ++ni) {
      b[ni][0] = *(const bf16x8*)(sB + offB[ni]);
      b[ni][1] = *(const bf16x8*)(sB + (offB[ni] ^ 32));
    }
#pragma unroll
    for (int kk = 0; kk < 2; ++kk)
#pragma unroll
      for (int mi = 0; mi < 4; ++mi)
#pragma unroll
        for (int ni = 0; ni < 4; ++ni)
          acc[mi][ni] = __builtin_amdgcn_mfma_f32_16x16x32_bf16(a[mi][kk], b[ni][kk],
                                                                acc[mi][ni], 0, 0, 0);
    asm volatile("" ::: "memory");
    __builtin_amdgcn_s_barrier();
    asm volatile("" ::: "memory");
    p ^= 1;
  }

  if constexpr (!OUT_F32) {
#pragma unroll
    for (int mi = 0; mi < 4; ++mi)
#pragma unroll
      for (int ni = 0; ni < 4; ++ni) {
        int col = wc + ni * 16 + lm;
        float bv = bias[col0 + col];
#pragma unroll
        for (int r = 0; r < 4; ++r)
          smem[(wr + mi * 16 + lk * 4 + r) * 136 + col] = f2bf(acc[mi][ni][r] + bv);
      }
    __syncthreads();
    const int rr = t >> 1, seg = t & 1;
    u16* dst = (u16*)Cp + (size_t)(row0 + rr) * Nn + col0 + seg * 64;
    const u16* src = smem + rr * 136 + seg * 64;
#pragma unroll
    for (int i = 0; i < 8; ++i)
      *(int4*)(dst + i * 8) = *(const int4*)(src + i * 8);
  } else {
    float* smf = (float*)smem;
    for (int half = 0; half < 2; ++half) {
      __syncthreads();
      if ((w >> 1) == half) {
#pragma unroll
        for (int mi = 0; mi < 4; ++mi)
#pragma unroll
          for (int ni = 0; ni < 4; ++ni) {
            int col = wc + ni * 16 + lm;
            float bv = bias[col0 + col];
#pragma unroll
            for (int r = 0; r < 4; ++r)
              smf[(mi * 16 + lk * 4 + r) * 132 + col] = acc[mi][ni][r] + bv;
          }
      }
      __syncthreads();
      const int rr = t >> 2, seg = t & 3;
      float* dst = (float*)Cp + (size_t)(row0 + half * 64 + rr) * Nn + col0 + seg * 32;
      const float* src = smf + rr * 132 + seg * 32;
#pragma unroll
      for (int i = 0; i < 8; ++i)
        *(float4*)(dst + i * 4) = *(const float4*)(src + i * 4);
    }
  }
}

// ---------------- fused window attention (R13 structure, VGPR-lean) ----------------
// Block = window, 4 waves; wave wv handles heads 4wv..4wv+3 sequentially.
// Swapped QK^T (mfma(K,Q)): lane (lm,lk) holds S[q=lm+16mi][k=ni*16+lk*4+r];
// softmax row lives in 4 lanes {lm,+16,+32,+48} -> 2-shuffle reduce.
// bias+mask enter as the MFMA C operand. All LDS wave-private: NO barriers.
__global__ __launch_bounds__(256) void k_attn(const u16* __restrict__ qkv,
                                              const float* __restrict__ biasM,
                                              const float* __restrict__ maskT,
                                              u16* __restrict__ aout) {
  __shared__ u16 sm[4 * 3264];      // per wave: sV 32x68 (V^T) + sP 16x68
  const int wdx = blockIdx.x;
  const int mw  = wdx & 63;
  const int t   = threadIdx.x;
  const int wv  = t >> 6;
  const int l   = t & 63;
  const int lm  = l & 15, lk = l >> 4;
  const size_t tb = (size_t)wdx * NTOK;
  const u16* base = qkv + tb * 1536;
  u16* sV = sm + wv * 3264;
  u16* sP = sV + 2176;

  const int4  iz = make_int4(0, 0, 0, 0);
  const f32x4 fz = {0.f, 0.f, 0.f, 0.f};
  const float* mT = maskT + (mw << 12);

  for (int hh = 0; hh < 4; ++hh) {
    const int h = (wv << 2) + hh;

    // stage V^T (wave-private): lane l = token row; 32 d-values scattered
    {
      int4 vv[4] = {iz, iz, iz, iz};
      if (l < NTOK) {
        const u16* vp = base + (size_t)l * 1536 + 1024 + h * 32;
#pragma unroll
        for (int i = 0; i < 4; ++i) vv[i] = *(const int4*)(vp + i * 8);
      }
      const u16* u = (const u16*)vv;
#pragma unroll
      for (int d = 0; d < 32; ++d) sV[d * 68 + l] = u[d];
    }

    // K fragments (all 64 k-rows)
    bf16x8 kf[4];
#pragma unroll
    for (int ni = 0; ni < 4; ++ni) {
      int krow = ni * 16 + lm;
      int4 ki = (krow < NTOK)
        ? *(const int4*)(base + (size_t)krow * 1536 + 512 + h * 32 + lk * 8) : iz;
      kf[ni] = __builtin_bit_cast(bf16x8, ki);
    }

    // V^T fragments (after same-wave LDS writes; lgkmcnt ordering is automatic)
    bf16x8 vb[2][2];
#pragma unroll
    for (int kt = 0; kt < 2; ++kt)
#pragma unroll
      for (int df = 0; df < 2; ++df)
        vb[kt][df] = *(const bf16x8*)(sV + (df * 16 + lm) * 68 + kt * 32 + lk * 8);

    const float* bM = biasM + (h << 12);

#pragma unroll
    for (int mi = 0; mi < 4; ++mi) {
      const int qrow = mi * 16 + lm;
      int4 qi = (qrow < NTOK)
        ? *(const int4*)(base + (size_t)qrow * 1536 + h * 32 + lk * 8) : iz;
      bf16x8 qf = __builtin_bit_cast(bf16x8, qi);

      f32x4 st[4];
#pragma unroll
      for (int ni = 0; ni < 4; ++ni) {
        const int o4 = (qrow << 6) + ni * 16 + lk * 4;
        float4 b4 = *(const float4*)(bM + o4);
        float4 m4 = *(const float4*)(mT + o4);
        f32x4 ci = {b4.x + m4.x, b4.y + m4.y, b4.z + m4.z, b4.w + m4.w};
        st[ni] = __builtin_amdgcn_mfma_f32_16x16x32_bf16(kf[ni], qf, ci, 0, 0, 0);
      }

      // lane-local softmax row (4-lane group reduce)
      float mx = -3e38f;
#pragma unroll
      for (int ni = 0; ni < 4; ++ni)
#pragma unroll
        for (int r = 0; r < 4; ++r) mx = fmaxf(mx, st[ni][r]);
      mx = fmaxf(mx, __shfl_xor(mx, 16, 64));
      mx = fmaxf(mx, __shfl_xor(mx, 32, 64));
      float sum = 0.f;
#pragma unroll
      for (int ni = 0; ni < 4; ++ni)
#pragma unroll
        for (int r = 0; r < 4; ++r) {
          float p = __expf(st[ni][r] - mx);
          st[ni][r] = p;
          sum += p;
        }
      sum += __shfl_xor(sum, 16, 64);
      sum += __shfl_xor(sum, 32, 64);
      const float rinv = __builtin_amdgcn_rcpf(sum);

      // normalized P -> wave-private LDS (b64 writes, k-contiguous)
#pragma unroll
      for (int ni = 0; ni < 4; ++ni) {
        u16 pk[4] = {f2bf(st[ni][0] * rinv), f2bf(st[ni][1] * rinv),
                     f2bf(st[ni][2] * rinv), f2bf(st[ni][3] * rinv)};
        *(int2*)(sP + lm * 68 + ni * 16 + lk * 4) = *(const int2*)pk;
      }

      // O = P @ V^T-frag: D[q=lk*4+r][d=df*16+lm]
      f32x4 o0 = fz, o1 = fz;
#pragma unroll
      for (int kt = 0; kt < 2; ++kt) {
        bf16x8 pa = *(const bf16x8*)(sP + lm * 68 + kt * 32 + lk * 8);
        o0 = __builtin_amdgcn_mfma_f32_16x16x32_bf16(pa, vb[kt][0], o0, 0, 0, 0);
        o1 = __builtin_amdgcn_mfma_f32_16x16x32_bf16(pa, vb[kt][1], o1, 0, 0, 0);
      }

#pragma unroll
      for (int r = 0; r < 4; ++r) {
        int tok = mi * 16 + lk * 4 + r;
        if (tok < NTOK) {
          float inv = 1.f;
          size_t ob = (tb + tok) * CH + h * 32;
          aout[ob + lm]      = f2bf(o0[r] * inv);
          aout[ob + 16 + lm] = f2bf(o1[r] * inv);
        }
      }
    }
  }
}

extern "C" void kernel_launch(void* const* d_in, const int* in_sizes, int n_in,
                              void* d_out, int out_size, void* d_ws, size_t ws_size,
                              hipStream_t stream) {
  const float* x      = (const float*)d_in[0];
  const float* qkv_b  = (const float*)d_in[2];
  const float* proj_b = (const float*)d_in[4];
  const float* btab   = (const float*)d_in[5];

  char* ws   = (char*)d_ws;
  u16* Wt    = (u16*)ws;                                  // 1,572,864 B
  u16* Pt    = (u16*)(ws + 1572864);                      //   524,288 B
  u16* qkv   = (u16*)(ws + 2097152);                      // 308,281,344 B
  u16* aout  = (u16*)(ws + 2097152 + 308281344ull);       // 102,760,448 B (aliased xb)
  u16* xb    = aout;                                      // dead once attn writes aout
  float* biasM = (float*)(ws + 2097152 + 308281344ull + 102760448ull);  // 262,144 B
  float* maskT = biasM + 65536;                           // 1,048,576 B
  float* bias2 = maskT + 262144;                          //     6,144 B
  float* out = (float*)d_out;

  k_wprep<<<1024, 256, 0, stream>>>((const float*)d_in[1], (const float*)d_in[3], Wt, Pt);
  k_xcast<<<25088, 256, 0, stream>>>(x, xb);
  k_tabs<<<1280, 256, 0, stream>>>(btab, qkv_b, biasM, maskT, bias2);
  k_gemm<0><<<784 * 12, 256, 0, stream>>>(xb, Wt, bias2, (void*)qkv, 100352, 1536, 512, 12);
  k_attn<<<2048, 256, 0, stream>>>(qkv, biasM, maskT, aout);
  k_gemm<1><<<784 * 4, 256, 0, stream>>>(aout, Pt, proj_b, (void*)out, 100352, 512, 512, 4);
}